// Round 2
// baseline (1154.407 us; speedup 1.0000x reference)
//
#include <hip/hip_runtime.h>
#include <cstdint>
#include <cstddef>

// ---------------------------------------------------------------------------
// MultiHeadAttention (B=2, S=2048, D=1024, H=16, depth=64) + LayerNorm.
// ALL I/O fp32. Outputs: out [B,S,D] then attn [B,H,S,S] concat flat (fp32).
// Internals: split-bf16 (hi/lo, 3-MFMA) for Q/K-proj and QK^T (high precision,
// feeds the tightly-thresholded attn output); single bf16 MFMA for V/PV/proj.
// ---------------------------------------------------------------------------

#define S_LEN 2048
#define D_MODEL 1024
#define N_HEADS 16
#define DEPTH 64
#define BATCH 2
#define OUT0_ELEMS (BATCH * S_LEN * D_MODEL)          // 4,194,304

typedef __attribute__((ext_vector_type(8))) short short8;     // 8 bf16 = 4 VGPR
typedef __attribute__((ext_vector_type(4))) float float4v;
typedef __attribute__((ext_vector_type(4))) uint16_t u16x4;

__device__ __forceinline__ float bf2f(uint16_t h) {
    uint32_t u = ((uint32_t)h) << 16;
    return __builtin_bit_cast(float, u);
}
__device__ __forceinline__ uint16_t f2bf(float f) {
    uint32_t u = __builtin_bit_cast(uint32_t, f);
    u += 0x7fffu + ((u >> 16) & 1u);   // round-to-nearest-even
    return (uint16_t)(u >> 16);
}

// async 16B global->LDS; HW: wave-uniform base + lane*16 (layout matches t*16)
__device__ __forceinline__ void async_load16(const void* g, void* l) {
    __builtin_amdgcn_global_load_lds(
        (const __attribute__((address_space(1))) void*)g,
        (__attribute__((address_space(3))) void*)l, 16, 0, 0);
}

// ---------------------------------------------------------------------------
// Single-precision bf16 GEMM core: C[128x128] = A[128xK] * Bt[128xK]^T.
// 256 threads = 4 waves (2x2); wave does 64x64 via 4x4 MFMA 16x16x32 tiles.
// ---------------------------------------------------------------------------
template <typename Epi>
__device__ __forceinline__ void gemm_core_128x128(
    const uint16_t* __restrict__ A, const uint16_t* __restrict__ Bt,
    int K, Epi&& epi)
{
    __shared__ __align__(16) uint16_t la[128 * 32];
    __shared__ __align__(16) uint16_t lb[128 * 32];
    const int t = threadIdx.x;
    const int wave = t >> 6, lane = t & 63;
    const int quad = lane >> 4, lr = lane & 15;
    const int wm = (wave & 1) * 64, wn = (wave >> 1) * 64;
    const int row_a = t >> 2;          // 0..63
    const int kk = (t & 3) * 8;

    float4v acc[4][4] = {};

    for (int k0 = 0; k0 < K; k0 += 32) {
        async_load16(A  + (row_a      ) * K + k0 + kk, (char*)la + t * 16);
        async_load16(A  + (row_a + 64 ) * K + k0 + kk, (char*)la + 4096 + t * 16);
        async_load16(Bt + (row_a      ) * K + k0 + kk, (char*)lb + t * 16);
        async_load16(Bt + (row_a + 64 ) * K + k0 + kk, (char*)lb + 4096 + t * 16);
        __syncthreads();

        short8 af[4], bfr[4];
        #pragma unroll
        for (int i = 0; i < 4; i++)
            af[i] = *(const short8*)&la[(wm + i * 16 + lr) * 32 + quad * 8];
        #pragma unroll
        for (int j = 0; j < 4; j++)
            bfr[j] = *(const short8*)&lb[(wn + j * 16 + lr) * 32 + quad * 8];
        #pragma unroll
        for (int i = 0; i < 4; i++)
            #pragma unroll
            for (int j = 0; j < 4; j++)
                acc[i][j] = __builtin_amdgcn_mfma_f32_16x16x32_bf16(
                    af[i], bfr[j], acc[i][j], 0, 0, 0);
        __syncthreads();
    }

    #pragma unroll
    for (int i = 0; i < 4; i++)
        #pragma unroll
        for (int j = 0; j < 4; j++)
            #pragma unroll
            for (int r = 0; r < 4; r++)
                epi(wm + i * 16 + quad * 4 + r, wn + j * 16 + lr, acc[i][j][r]);
}

// ---------------------------------------------------------------------------
// Split-precision core: A ~= Ah+Al, B ~= Bh+Bl (bf16 each). 3 MFMAs per tile:
// D = Ah*Bh + Ah*Bl + Al*Bh   (Al*Bl term ~2^-18, omitted). fp32-grade result.
// ---------------------------------------------------------------------------
template <typename Epi>
__device__ __forceinline__ void gemm_split_128x128(
    const uint16_t* __restrict__ Ah, const uint16_t* __restrict__ Al,
    const uint16_t* __restrict__ Bh, const uint16_t* __restrict__ Bl,
    int K, Epi&& epi)
{
    __shared__ __align__(16) uint16_t lah[128 * 32];
    __shared__ __align__(16) uint16_t lal[128 * 32];
    __shared__ __align__(16) uint16_t lbh[128 * 32];
    __shared__ __align__(16) uint16_t lbl[128 * 32];
    const int t = threadIdx.x;
    const int wave = t >> 6, lane = t & 63;
    const int quad = lane >> 4, lr = lane & 15;
    const int wm = (wave & 1) * 64, wn = (wave >> 1) * 64;
    const int row_a = t >> 2;
    const int kk = (t & 3) * 8;

    float4v acc[4][4] = {};

    for (int k0 = 0; k0 < K; k0 += 32) {
        async_load16(Ah + (row_a     ) * K + k0 + kk, (char*)lah + t * 16);
        async_load16(Ah + (row_a + 64) * K + k0 + kk, (char*)lah + 4096 + t * 16);
        async_load16(Al + (row_a     ) * K + k0 + kk, (char*)lal + t * 16);
        async_load16(Al + (row_a + 64) * K + k0 + kk, (char*)lal + 4096 + t * 16);
        async_load16(Bh + (row_a     ) * K + k0 + kk, (char*)lbh + t * 16);
        async_load16(Bh + (row_a + 64) * K + k0 + kk, (char*)lbh + 4096 + t * 16);
        async_load16(Bl + (row_a     ) * K + k0 + kk, (char*)lbl + t * 16);
        async_load16(Bl + (row_a + 64) * K + k0 + kk, (char*)lbl + 4096 + t * 16);
        __syncthreads();

        short8 fah[4], fal[4], fbh[4], fbl[4];
        #pragma unroll
        for (int i = 0; i < 4; i++) {
            int off = (wm + i * 16 + lr) * 32 + quad * 8;
            fah[i] = *(const short8*)&lah[off];
            fal[i] = *(const short8*)&lal[off];
        }
        #pragma unroll
        for (int j = 0; j < 4; j++) {
            int off = (wn + j * 16 + lr) * 32 + quad * 8;
            fbh[j] = *(const short8*)&lbh[off];
            fbl[j] = *(const short8*)&lbl[off];
        }
        #pragma unroll
        for (int i = 0; i < 4; i++)
            #pragma unroll
            for (int j = 0; j < 4; j++) {
                acc[i][j] = __builtin_amdgcn_mfma_f32_16x16x32_bf16(
                    fah[i], fbh[j], acc[i][j], 0, 0, 0);
                acc[i][j] = __builtin_amdgcn_mfma_f32_16x16x32_bf16(
                    fah[i], fbl[j], acc[i][j], 0, 0, 0);
                acc[i][j] = __builtin_amdgcn_mfma_f32_16x16x32_bf16(
                    fal[i], fbh[j], acc[i][j], 0, 0, 0);
            }
        __syncthreads();
    }

    #pragma unroll
    for (int i = 0; i < 4; i++)
        #pragma unroll
        for (int j = 0; j < 4; j++)
            #pragma unroll
            for (int r = 0; r < 4; r++)
                epi(wm + i * 16 + quad * 4 + r, wn + j * 16 + lr, acc[i][j][r]);
}

// ---------------------------------------------------------------------------
// Prep kernels
// ---------------------------------------------------------------------------

// Transpose fp32 weights; Wq,Wk -> hi/lo split bf16; Wv,Wo -> single bf16.
__global__ __launch_bounds__(256) void prep_w_kernel(
    const float* __restrict__ wq, const float* __restrict__ wk,
    const float* __restrict__ wv, const float* __restrict__ wo,
    uint16_t* __restrict__ wqh, uint16_t* __restrict__ wql,
    uint16_t* __restrict__ wkh, uint16_t* __restrict__ wkl,
    uint16_t* __restrict__ wvt, uint16_t* __restrict__ wot)
{
    const int z = blockIdx.z;
    const float* src = z == 0 ? wq : z == 1 ? wk : z == 2 ? wv : wo;
    int idx = blockIdx.x * 256 + threadIdx.x;       // 0..1M-1
    int n = idx >> 10, k = idx & 1023;
    float v = src[k * D_MODEL + n];                 // gather (transpose)
    uint16_t hi = f2bf(v);
    if (z == 0) { wqh[idx] = hi; wql[idx] = f2bf(v - bf2f(hi)); }
    else if (z == 1) { wkh[idx] = hi; wkl[idx] = f2bf(v - bf2f(hi)); }
    else if (z == 2) { wvt[idx] = hi; }
    else { wot[idx] = hi; }
}

// query,key -> hi/lo bf16; value -> single bf16. Each thread: 4 elems.
__global__ __launch_bounds__(256) void split_x_kernel(
    const float* __restrict__ q, const float* __restrict__ k,
    const float* __restrict__ v,
    uint16_t* __restrict__ xqh, uint16_t* __restrict__ xql,
    uint16_t* __restrict__ xkh, uint16_t* __restrict__ xkl,
    uint16_t* __restrict__ xv)
{
    const int z = blockIdx.z;
    const float* src = z == 0 ? q : z == 1 ? k : v;
    int idx = (blockIdx.x * 256 + threadIdx.x) * 4;
    float4v f = *(const float4v*)(src + idx);
    u16x4 hi, lo;
    #pragma unroll
    for (int e = 0; e < 4; e++) {
        hi[e] = f2bf(f[e]);
        lo[e] = f2bf(f[e] - bf2f(hi[e]));
    }
    if (z == 0) { *(u16x4*)(xqh + idx) = hi; *(u16x4*)(xql + idx) = lo; }
    else if (z == 1) { *(u16x4*)(xkh + idx) = hi; *(u16x4*)(xkl + idx) = lo; }
    else { *(u16x4*)(xv + idx) = hi; }
}

// ---------------------------------------------------------------------------
// Main pipeline
// ---------------------------------------------------------------------------

// Q/K projection (split, precise): X@W + b -> hi/lo bf16 in [B,H,S,64].
__global__ __launch_bounds__(256) void qkproj_kernel(
    const uint16_t* __restrict__ xqh, const uint16_t* __restrict__ xql,
    const uint16_t* __restrict__ xkh, const uint16_t* __restrict__ xkl,
    const uint16_t* __restrict__ wqh, const uint16_t* __restrict__ wql,
    const uint16_t* __restrict__ wkh, const uint16_t* __restrict__ wkl,
    const float* __restrict__ bq, const float* __restrict__ bk,
    uint16_t* __restrict__ qh, uint16_t* __restrict__ ql,
    uint16_t* __restrict__ kh, uint16_t* __restrict__ kl)
{
    const int z = blockIdx.z;
    const uint16_t* Ah = (z == 0 ? xqh : xkh) + (size_t)blockIdx.y * 128 * D_MODEL;
    const uint16_t* Al = (z == 0 ? xql : xkl) + (size_t)blockIdx.y * 128 * D_MODEL;
    const uint16_t* Bh = (z == 0 ? wqh : wkh) + (size_t)blockIdx.x * 128 * D_MODEL;
    const uint16_t* Bl = (z == 0 ? wql : wkl) + (size_t)blockIdx.x * 128 * D_MODEL;
    const float* bias = z == 0 ? bq : bk;
    uint16_t* oh = z == 0 ? qh : kh;
    uint16_t* ol = z == 0 ? ql : kl;
    const int m0 = blockIdx.y * 128, n0 = blockIdx.x * 128;

    gemm_split_128x128(Ah, Al, Bh, Bl, D_MODEL, [&](int r, int c, float v) {
        int m = m0 + r, n = n0 + c;
        float val = v + bias[n];
        int b = m >> 11, s2 = m & 2047;
        int h = n >> 6, dp = n & 63;
        size_t o = (((size_t)(b * N_HEADS + h)) * S_LEN + s2) * DEPTH + dp;
        uint16_t hi = f2bf(val);
        oh[o] = hi;
        ol[o] = f2bf(val - bf2f(hi));
    });
}

// V projection (single bf16): value@Wv + bv -> vt [B,H,64,S] (transposed).
__global__ __launch_bounds__(256) void vproj_kernel(
    const uint16_t* __restrict__ xv, const uint16_t* __restrict__ wvt,
    const float* __restrict__ bv, uint16_t* __restrict__ vt)
{
    const uint16_t* A  = xv + (size_t)blockIdx.y * 128 * D_MODEL;
    const uint16_t* Bt = wvt + (size_t)blockIdx.x * 128 * D_MODEL;
    const int m0 = blockIdx.y * 128, n0 = blockIdx.x * 128;

    gemm_core_128x128(A, Bt, D_MODEL, [&](int r, int c, float v) {
        int m = m0 + r, n = n0 + c;
        int b = m >> 11, s2 = m & 2047;
        int h = n >> 6, dp = n & 63;
        vt[(((size_t)(b * N_HEADS + h)) * DEPTH + dp) * S_LEN + s2] = f2bf(v + bv[n]);
    });
}

// logits = q@k^T / 8 (split, precise) -> fp32 straight into d_out attn region.
__global__ __launch_bounds__(256) void qk_kernel(
    const uint16_t* __restrict__ qh, const uint16_t* __restrict__ ql,
    const uint16_t* __restrict__ kh, const uint16_t* __restrict__ kl,
    float* __restrict__ attn)
{
    const int bh = blockIdx.z;
    size_t ao = ((size_t)bh * S_LEN + blockIdx.y * 128) * DEPTH;
    size_t bo = ((size_t)bh * S_LEN + blockIdx.x * 128) * DEPTH;
    float* out = attn + (size_t)bh * S_LEN * S_LEN;
    const int m0 = blockIdx.y * 128, n0 = blockIdx.x * 128;

    gemm_split_128x128(qh + ao, ql + ao, kh + bo, kl + bo, DEPTH,
        [&](int r, int c, float v) {
            out[(size_t)(m0 + r) * S_LEN + (n0 + c)] = v * 0.125f;
        });
}

// Row softmax, fp32 in-place. One 256-thread block per row (2048 floats).
__global__ __launch_bounds__(256) void softmax_kernel(float* __restrict__ attn)
{
    const int t = threadIdx.x;
    float* p = attn + (size_t)blockIdx.x * S_LEN + t * 8;
    float4v a = *(const float4v*)p;
    float4v b = *(const float4v*)(p + 4);
    float x[8] = {a[0], a[1], a[2], a[3], b[0], b[1], b[2], b[3]};

    float m = x[0];
    #pragma unroll
    for (int j = 1; j < 8; j++) m = fmaxf(m, x[j]);
    #pragma unroll
    for (int off = 32; off > 0; off >>= 1) m = fmaxf(m, __shfl_xor(m, off));

    __shared__ float red[8];
    const int wave = t >> 6, lane = t & 63;
    if (lane == 0) red[wave] = m;
    __syncthreads();
    m = fmaxf(fmaxf(red[0], red[1]), fmaxf(red[2], red[3]));

    float s = 0.f;
    #pragma unroll
    for (int j = 0; j < 8; j++) { x[j] = __expf(x[j] - m); s += x[j]; }
    #pragma unroll
    for (int off = 32; off > 0; off >>= 1) s += __shfl_xor(s, off);
    if (lane == 0) red[4 + wave] = s;
    __syncthreads();
    s = (red[4] + red[5]) + (red[6] + red[7]);

    float inv = 1.0f / s;
    #pragma unroll
    for (int j = 0; j < 8; j++) x[j] *= inv;
    *(float4v*)p       = float4v{x[0], x[1], x[2], x[3]};
    *(float4v*)(p + 4) = float4v{x[4], x[5], x[6], x[7]};
}

// ctx = attn @ v -> [B,S,1024] bf16. A staged fp32->bf16 manually; B async.
// 128x64 tile: 4 waves 2x2, each wave 64x32.
__global__ __launch_bounds__(256) void av_kernel(
    const float* __restrict__ attn, const uint16_t* __restrict__ vt,
    uint16_t* __restrict__ ctx)
{
    __shared__ __align__(16) uint16_t la[128 * 32];
    __shared__ __align__(16) uint16_t lb[64 * 32];
    const int bh = blockIdx.y;
    const int b = bh >> 4, h = bh & 15;
    const int m0 = blockIdx.x * 128;
    const float* A = attn + (size_t)bh * S_LEN * S_LEN + (size_t)m0 * S_LEN;
    const uint16_t* Bt = vt + (size_t)bh * DEPTH * S_LEN;

    const int t = threadIdx.x;
    const int wave = t >> 6, lane = t & 63;
    const int quad = lane >> 4, lr = lane & 15;
    const int wm = (wave & 1) * 64, wn = (wave >> 1) * 32;
    const int row_b = t >> 2;          // 0..63
    const int kk = (t & 3) * 8;
    const int ra = t >> 1;             // 0..127 (A staging row)
    const int hc = (t & 1) * 16;       // A staging col offset

    float4v acc[4][2] = {};

    for (int k0 = 0; k0 < S_LEN; k0 += 32) {
        async_load16(Bt + (size_t)row_b * S_LEN + k0 + kk, (char*)lb + t * 16);
        const float4v* src = (const float4v*)(A + (size_t)ra * S_LEN + k0 + hc);
        short8 p0, p1;
        #pragma unroll
        for (int j = 0; j < 2; j++) {
            float4v f = src[j];
            #pragma unroll
            for (int e = 0; e < 4; e++) p0[j * 4 + e] = (short)f2bf(f[e]);
        }
        #pragma unroll
        for (int j = 0; j < 2; j++) {
            float4v f = src[2 + j];
            #pragma unroll
            for (int e = 0; e < 4; e++) p1[j * 4 + e] = (short)f2bf(f[e]);
        }
        *(short8*)&la[ra * 32 + hc] = p0;
        *(short8*)&la[ra * 32 + hc + 8] = p1;
        __syncthreads();

        short8 af[4], bfr[2];
        #pragma unroll
        for (int i = 0; i < 4; i++)
            af[i] = *(const short8*)&la[(wm + i * 16 + lr) * 32 + quad * 8];
        #pragma unroll
        for (int j = 0; j < 2; j++)
            bfr[j] = *(const short8*)&lb[(wn + j * 16 + lr) * 32 + quad * 8];
        #pragma unroll
        for (int i = 0; i < 4; i++)
            #pragma unroll
            for (int j = 0; j < 2; j++)
                acc[i][j] = __builtin_amdgcn_mfma_f32_16x16x32_bf16(
                    af[i], bfr[j], acc[i][j], 0, 0, 0);
        __syncthreads();
    }

    #pragma unroll
    for (int i = 0; i < 4; i++)
        #pragma unroll
        for (int j = 0; j < 2; j++)
            #pragma unroll
            for (int r = 0; r < 4; r++) {
                int s2 = m0 + wm + i * 16 + quad * 4 + r;
                int c = wn + j * 16 + lr;
                ctx[((size_t)(b * S_LEN + s2)) * D_MODEL + h * DEPTH + c] = f2bf(acc[i][j][r]);
            }
}

// out-proj: ctx @ Wo + bo -> fp32 scratch (pre-LN)
__global__ __launch_bounds__(256) void proj_kernel(
    const uint16_t* __restrict__ ctx, const uint16_t* __restrict__ wot,
    const float* __restrict__ bo, float* __restrict__ pre)
{
    const uint16_t* A  = ctx + (size_t)blockIdx.y * 128 * D_MODEL;
    const uint16_t* Bt = wot + (size_t)blockIdx.x * 128 * D_MODEL;
    const int m0 = blockIdx.y * 128, n0 = blockIdx.x * 128;

    gemm_core_128x128(A, Bt, D_MODEL, [&](int r, int c, float v) {
        pre[(size_t)(m0 + r) * D_MODEL + (n0 + c)] = v + bo[n0 + c];
    });
}

// LayerNorm (eps=1e-3, population var) -> fp32 out
__global__ __launch_bounds__(256) void ln_kernel(
    const float* __restrict__ pre, const float* __restrict__ gamma,
    const float* __restrict__ beta, float* __restrict__ out)
{
    const int t = threadIdx.x;
    const int row = blockIdx.x;
    const float4v x = *(const float4v*)(pre + (size_t)row * D_MODEL + t * 4);
    float s  = x[0] + x[1] + x[2] + x[3];
    float ss = x[0]*x[0] + x[1]*x[1] + x[2]*x[2] + x[3]*x[3];
    #pragma unroll
    for (int off = 32; off > 0; off >>= 1) {
        s  += __shfl_xor(s, off);
        ss += __shfl_xor(ss, off);
    }
    __shared__ float red[8];
    const int wave = t >> 6, lane = t & 63;
    if (lane == 0) { red[wave] = s; red[4 + wave] = ss; }
    __syncthreads();
    s  = (red[0] + red[1]) + (red[2] + red[3]);
    ss = (red[4] + red[5]) + (red[6] + red[7]);
    float mu  = s * (1.0f / 1024.0f);
    float var = ss * (1.0f / 1024.0f) - mu * mu;
    float inv = rsqrtf(var + 1e-3f);

    float4v g = *(const float4v*)(gamma + t * 4);
    float4v bb = *(const float4v*)(beta + t * 4);
    float4v o;
    #pragma unroll
    for (int j = 0; j < 4; j++)
        o[j] = (x[j] - mu) * inv * g[j] + bb[j];
    *(float4v*)(out + (size_t)row * D_MODEL + t * 4) = o;
}

// ---------------------------------------------------------------------------

extern "C" void kernel_launch(void* const* d_in, const int* in_sizes, int n_in,
                              void* d_out, int out_size, void* d_ws, size_t ws_size,
                              hipStream_t stream)
{
    const float* q_in = (const float*)d_in[0];
    const float* k_in = (const float*)d_in[1];
    const float* v_in = (const float*)d_in[2];
    const float* Wq   = (const float*)d_in[3];
    const float* bq   = (const float*)d_in[4];
    const float* Wk   = (const float*)d_in[5];
    const float* bk   = (const float*)d_in[6];
    const float* Wv   = (const float*)d_in[7];
    const float* bv   = (const float*)d_in[8];
    const float* Wo   = (const float*)d_in[9];
    const float* bo   = (const float*)d_in[10];
    const float* gamma= (const float*)d_in[11];
    const float* beta = (const float*)d_in[12];

    char* ws = (char*)d_ws;
    uint16_t* wqh = (uint16_t*)(ws);                      // 2 MB each (1M bf16)
    uint16_t* wql = (uint16_t*)(ws + (2u  << 20));
    uint16_t* wkh = (uint16_t*)(ws + (4u  << 20));
    uint16_t* wkl = (uint16_t*)(ws + (6u  << 20));
    uint16_t* wvt = (uint16_t*)(ws + (8u  << 20));
    uint16_t* wot = (uint16_t*)(ws + (10u << 20));
    uint16_t* xqh = (uint16_t*)(ws + (12u << 20));        // 8 MB each (4M bf16)
    uint16_t* xql = (uint16_t*)(ws + (20u << 20));
    uint16_t* xkh = (uint16_t*)(ws + (28u << 20));
    uint16_t* xkl = (uint16_t*)(ws + (36u << 20));
    uint16_t* xv  = (uint16_t*)(ws + (44u << 20));
    uint16_t* qh  = (uint16_t*)(ws + (52u << 20));        // [B,H,S,64] hi/lo
    uint16_t* ql  = (uint16_t*)(ws + (60u << 20));
    uint16_t* kh  = (uint16_t*)(ws + (68u << 20));
    uint16_t* kl  = (uint16_t*)(ws + (76u << 20));
    uint16_t* vt  = (uint16_t*)(ws + (84u << 20));        // [B,H,64,S]
    uint16_t* ctx = (uint16_t*)(ws + (92u << 20));        // [B,S,1024] bf16
    float*    pre = (float*)   (ws + (100u << 20));       // 16 MB fp32

    float* out  = (float*)d_out;                          // [B,S,1024] fp32
    float* attn = out + OUT0_ELEMS;                       // [B,H,S,S] fp32

    prep_w_kernel<<<dim3(4096, 1, 4), 256, 0, stream>>>(
        Wq, Wk, Wv, Wo, wqh, wql, wkh, wkl, wvt, wot);
    split_x_kernel<<<dim3(4096, 1, 3), 256, 0, stream>>>(
        q_in, k_in, v_in, xqh, xql, xkh, xkl, xv);
    qkproj_kernel<<<dim3(8, 32, 2), 256, 0, stream>>>(
        xqh, xql, xkh, xkl, wqh, wql, wkh, wkl, bq, bk, qh, ql, kh, kl);
    vproj_kernel<<<dim3(8, 32, 1), 256, 0, stream>>>(xv, wvt, bv, vt);
    qk_kernel<<<dim3(16, 16, 32), 256, 0, stream>>>(qh, ql, kh, kl, attn);
    softmax_kernel<<<dim3(65536), 256, 0, stream>>>(attn);
    av_kernel<<<dim3(16, 32), 256, 0, stream>>>(attn, vt, ctx);
    proj_kernel<<<dim3(8, 32, 1), 256, 0, stream>>>(ctx, wot, bo, pre);
    ln_kernel<<<dim3(4096), 256, 0, stream>>>(pre, gamma, beta, out);
}